// Round 4
// baseline (386.395 us; speedup 1.0000x reference)
//
#include <hip/hip_runtime.h>

typedef _Float16 half2_t __attribute__((ext_vector_type(2)));

#define NB      256
#define NP1     10000
#define KNN     32
#define THREADS 1024
#define NWAVES  (THREADS / 64)
#define ITEMS   10            // ceil(NP1 / THREADS)
#define NEG_INF -1000000000.0f

static __device__ __forceinline__ unsigned pkrtz_u32(float x, float y) {
    auto h = __builtin_amdgcn_cvt_pkrtz(x, y);   // __fp16 ext_vector(2)
    return __builtin_bit_cast(unsigned, h);
}

static __device__ __forceinline__ half2_t uash(unsigned u) {
    return __builtin_bit_cast(half2_t, u);
}

#if defined(__has_builtin)
#if __has_builtin(__builtin_amdgcn_fdot2)
#define HAVE_FDOT2 1
#endif
#endif

static __device__ __forceinline__ float fdot2f(half2_t a, half2_t b, float c) {
#ifdef HAVE_FDOT2
    return __builtin_amdgcn_fdot2(a, b, c, false);
#else
    return c + (float)a[0] * (float)b[0] + (float)a[1] * (float)b[1];
#endif
}

__global__ __launch_bounds__(THREADS) void hybrid_scoring_kernel(
    const float* __restrict__ query,        // [B,2]
    const float* __restrict__ psi,          // [B,NP1,2]
    const int*   __restrict__ knn,          // [B,NP1,K]
    const int*   __restrict__ mask,         // [B,NP1] (bool pushed as int32)
    const float* __restrict__ cur,          // [B,2]
    const float* __restrict__ allc,         // [B,NP1,2]
    const float* __restrict__ lam_p,        // [1]
    const float* __restrict__ mu_p,         // [1]
    float* __restrict__ out)                // [B,NP1]
{
    __shared__ unsigned s_psi[NP1];         // packed f16x2 (x,y), ~40 KB
    __shared__ float red[NWAVES];

    const int b = blockIdx.x;
    const int t = threadIdx.x;

    const float lam = lam_p[0];
    const float mu  = mu_p[0];
    const float qx  = query[2*b],  qy = query[2*b+1];
    const float cx  = cur[2*b],    cy = cur[2*b+1];

    const float2* __restrict__ pb = (const float2*)(psi  + (long)b * NP1 * 2);
    const float2* __restrict__ ab = (const float2*)(allc + (long)b * NP1 * 2);
    const int4*   __restrict__ kb = (const int4*)(knn + (long)b * NP1 * KNN);
    const int*    __restrict__ mb = mask + (long)b * NP1;

    // ---- stage psi[b] into LDS as packed f16x2
    #pragma unroll
    for (int i = 0; i < ITEMS; ++i) {
        const int n = t + i * THREADS;
        if (n < NP1) {
            const float2 p = pb[n];
            s_psi[n] = pkrtz_u32(p.x, p.y);
        }
    }
    __syncthreads();

    const half2_t qh = uash(pkrtz_u32(qx, qy));

    // ---- scores
    float sc[ITEMS];
    #pragma unroll
    for (int i = 0; i < ITEMS; ++i) {
        const int n = t + i * THREADS;
        float v = -INFINITY;
        if (n < NP1) {
            const int4* kp = kb + n * (KNN / 4);
            const half2_t own = uash(s_psi[n]);
            float a0 = 0.f, a1 = 0.f, a2 = 0.f, a3 = 0.f;
            #pragma unroll
            for (int j = 0; j < KNN / 4; ++j) {
                const int4 id = kp[j];
                a0 = fdot2f(own, uash(s_psi[id.x]), a0);
                a1 = fdot2f(own, uash(s_psi[id.y]), a1);
                a2 = fdot2f(own, uash(s_psi[id.z]), a2);
                a3 = fdot2f(own, uash(s_psi[id.w]), a3);
            }
            const float2 ac = ab[n];
            const float dx = ac.x - cx, dy = ac.y - cy;
            const float dist = sqrtf(dx * dx + dy * dy);
            const float ctx = fdot2f(own, qh, 0.0f);
            v = ctx + lam * ((a0 + a1) + (a2 + a3)) - mu * dist;
            if (mb[n] != 0) v = NEG_INF;
        }
        sc[i] = v;
    }

    // ---- block max
    float m = -INFINITY;
    #pragma unroll
    for (int i = 0; i < ITEMS; ++i) m = fmaxf(m, sc[i]);
    #pragma unroll
    for (int off = 32; off > 0; off >>= 1) m = fmaxf(m, __shfl_xor(m, off));
    const int wid = t >> 6, lane = t & 63;
    if (lane == 0) red[wid] = m;
    __syncthreads();
    float M = red[0];
    #pragma unroll
    for (int w = 1; w < NWAVES; ++w) M = fmaxf(M, red[w]);
    __syncthreads();   // red reused below

    // ---- block sum of exp(sc - M)
    float s = 0.f;
    #pragma unroll
    for (int i = 0; i < ITEMS; ++i) s += __expf(sc[i] - M);
    #pragma unroll
    for (int off = 32; off > 0; off >>= 1) s += __shfl_xor(s, off);
    if (lane == 0) red[wid] = s;
    __syncthreads();
    float S = 0.f;
    #pragma unroll
    for (int w = 0; w < NWAVES; ++w) S += red[w];
    const float lse = M + logf(S);

    // ---- write log-softmax
    #pragma unroll
    for (int i = 0; i < ITEMS; ++i) {
        const int n = t + i * THREADS;
        if (n < NP1) out[(long)b * NP1 + n] = sc[i] - lse;
    }
}

extern "C" void kernel_launch(void* const* d_in, const int* in_sizes, int n_in,
                              void* d_out, int out_size, void* d_ws, size_t ws_size,
                              hipStream_t stream) {
    const float* query = (const float*)d_in[0];
    const float* psi   = (const float*)d_in[1];
    const int*   knn   = (const int*)d_in[2];
    const int*   mask  = (const int*)d_in[3];
    const float* cur   = (const float*)d_in[4];
    const float* allc  = (const float*)d_in[5];
    const float* lam   = (const float*)d_in[6];
    const float* mu    = (const float*)d_in[7];
    float* out = (float*)d_out;

    hybrid_scoring_kernel<<<NB, THREADS, 0, stream>>>(
        query, psi, knn, mask, cur, allc, lam, mu, out);
}

// Round 5
// 214.161 us; speedup vs baseline: 1.8042x; 1.8042x over previous
//
#include <hip/hip_runtime.h>

#define NB      256
#define NP1     10000
#define KNN     32
#define THREADS 1024
#define NWAVES  (THREADS / 64)
#define ITEMS   10            // ceil(NP1 / THREADS)
#define NEG_INF -1000000000.0f

__global__ __launch_bounds__(THREADS) void hybrid_scoring_kernel(
    const float* __restrict__ query,        // [B,2]
    const float* __restrict__ psi,          // [B,NP1,2]
    const int*   __restrict__ knn,          // [B,NP1,K]
    const int*   __restrict__ mask,         // [B,NP1] (bool pushed as int32)
    const float* __restrict__ cur,          // [B,2]
    const float* __restrict__ allc,         // [B,NP1,2]
    const float* __restrict__ lam_p,        // [1]
    const float* __restrict__ mu_p,         // [1]
    float* __restrict__ out)                // [B,NP1]
{
    __shared__ unsigned s_psi[NP1];         // packed bf16 (y<<16 | x), ~40 KB
    __shared__ float red[NWAVES];

    const int b = blockIdx.x;
    const int t = threadIdx.x;

    const float lam = lam_p[0];
    const float mu  = mu_p[0];
    const float qx  = query[2*b],  qy = query[2*b+1];
    const float cx  = cur[2*b],    cy = cur[2*b+1];

    const float2* __restrict__ pb = (const float2*)(psi  + (long)b * NP1 * 2);
    const float2* __restrict__ ab = (const float2*)(allc + (long)b * NP1 * 2);
    const int4*   __restrict__ kb = (const int4*)(knn + (long)b * NP1 * KNN);
    const int*    __restrict__ mb = mask + (long)b * NP1;

    // ---- stage psi[b] into LDS as packed bf16 pairs; keep own embedding in regs
    float2 pown[ITEMS];
    #pragma unroll
    for (int i = 0; i < ITEMS; ++i) {
        const int n = t + i * THREADS;
        float2 p = make_float2(0.f, 0.f);
        if (n < NP1) {
            p = pb[n];
            unsigned ux = __float_as_uint(p.x);
            unsigned uy = __float_as_uint(p.y);
            ux = (ux + 0x7FFFu + ((ux >> 16) & 1u)) >> 16;          // bf16 RNE, low half
            uy = (uy + 0x7FFFu + ((uy >> 16) & 1u)) & 0xFFFF0000u;  // bf16 RNE, high half
            s_psi[n] = uy | ux;
        }
        pown[i] = p;
    }
    __syncthreads();

    // ---- scores (no softmax work in the latency-critical loop)
    float sc[ITEMS];
    #pragma unroll
    for (int i = 0; i < ITEMS; ++i) {
        const int n = t + i * THREADS;
        float v = -INFINITY;
        if (n < NP1) {
            float nsx = 0.f, nsy = 0.f;
            const int4* kp = kb + n * (KNN / 4);
            #pragma unroll
            for (int j = 0; j < KNN / 4; ++j) {
                const int4 id = kp[j];
                const unsigned u0 = s_psi[id.x];
                const unsigned u1 = s_psi[id.y];
                const unsigned u2 = s_psi[id.z];
                const unsigned u3 = s_psi[id.w];
                nsx += __uint_as_float(u0 << 16) + __uint_as_float(u1 << 16)
                     + __uint_as_float(u2 << 16) + __uint_as_float(u3 << 16);
                nsy += __uint_as_float(u0 & 0xFFFF0000u) + __uint_as_float(u1 & 0xFFFF0000u)
                     + __uint_as_float(u2 & 0xFFFF0000u) + __uint_as_float(u3 & 0xFFFF0000u);
            }
            const float2 p  = pown[i];
            const float2 ac = ab[n];
            const float dx = ac.x - cx, dy = ac.y - cy;
            const float dist = sqrtf(dx * dx + dy * dy);
            v = p.x * qx + p.y * qy + lam * (p.x * nsx + p.y * nsy) - mu * dist;
            if (mb[n] != 0) v = NEG_INF;
        }
        sc[i] = v;
    }

    // ---- pass 1: block max
    float m = -INFINITY;
    #pragma unroll
    for (int i = 0; i < ITEMS; ++i) m = fmaxf(m, sc[i]);
    #pragma unroll
    for (int off = 32; off > 0; off >>= 1) m = fmaxf(m, __shfl_xor(m, off));
    const int wid = t >> 6, lane = t & 63;
    if (lane == 0) red[wid] = m;
    __syncthreads();
    float M = red[0];
    #pragma unroll
    for (int w = 1; w < NWAVES; ++w) M = fmaxf(M, red[w]);
    __syncthreads();   // red reused below

    // ---- pass 2: block sum of exp(sc - M)
    float s = 0.f;
    #pragma unroll
    for (int i = 0; i < ITEMS; ++i) s += __expf(sc[i] - M);
    #pragma unroll
    for (int off = 32; off > 0; off >>= 1) s += __shfl_xor(s, off);
    if (lane == 0) red[wid] = s;
    __syncthreads();
    float S = 0.f;
    #pragma unroll
    for (int w = 0; w < NWAVES; ++w) S += red[w];
    const float lse = M + logf(S);

    // ---- write log-softmax
    #pragma unroll
    for (int i = 0; i < ITEMS; ++i) {
        const int n = t + i * THREADS;
        if (n < NP1) out[(long)b * NP1 + n] = sc[i] - lse;
    }
}

extern "C" void kernel_launch(void* const* d_in, const int* in_sizes, int n_in,
                              void* d_out, int out_size, void* d_ws, size_t ws_size,
                              hipStream_t stream) {
    const float* query = (const float*)d_in[0];
    const float* psi   = (const float*)d_in[1];
    const int*   knn   = (const int*)d_in[2];
    const int*   mask  = (const int*)d_in[3];
    const float* cur   = (const float*)d_in[4];
    const float* allc  = (const float*)d_in[5];
    const float* lam   = (const float*)d_in[6];
    const float* mu    = (const float*)d_in[7];
    float* out = (float*)d_out;

    hybrid_scoring_kernel<<<NB, THREADS, 0, stream>>>(
        query, psi, knn, mask, cur, allc, lam, mu, out);
}

// Round 6
// 91.977 us; speedup vs baseline: 4.2010x; 2.3284x over previous
//
#include <hip/hip_runtime.h>

#define NB      256
#define NP1     10000
#define KNN     32
#define THREADS 1024
#define NWAVES  (THREADS / 64)
#define ITEMS   10            // ceil(NP1 / THREADS)
#define NGROUPS (NP1 / 8)     // 1250 groups of 8 nodes (exact)
#define NEG_INF -1000000000.0f

__global__ __launch_bounds__(THREADS) void hybrid_scoring_kernel(
    const float* __restrict__ query,        // [B,2]
    const float* __restrict__ psi,          // [B,NP1,2]
    const int*   __restrict__ knn,          // [B,NP1,K]
    const int*   __restrict__ mask,         // [B,NP1] (bool pushed as int32)
    const float* __restrict__ cur,          // [B,2]
    const float* __restrict__ allc,         // [B,NP1,2]
    const float* __restrict__ lam_p,        // [1]
    const float* __restrict__ mu_p,         // [1]
    float* __restrict__ out)                // [B,NP1]
{
    __shared__ unsigned s_psi[NP1];         // packed bf16 (y<<16 | x), 40 KB
    __shared__ float    s_intf[NP1];        // per-node interference dot, 40 KB
    __shared__ float    red[NWAVES];

    const int b    = blockIdx.x;
    const int t    = threadIdx.x;
    const int lane = t & 63;
    const int wid  = t >> 6;

    const float lam = lam_p[0];
    const float mu  = mu_p[0];
    const float qx  = query[2*b],  qy = query[2*b+1];
    const float cx  = cur[2*b],    cy = cur[2*b+1];

    const float2* __restrict__ pb = (const float2*)(psi  + (long)b * NP1 * 2);
    const float2* __restrict__ ab = (const float2*)(allc + (long)b * NP1 * 2);
    const int4*   __restrict__ kb = (const int4*)(knn + (long)b * NP1 * KNN);
    const int*    __restrict__ mb = mask + (long)b * NP1;

    // ---- stage psi[b] into LDS (packed bf16); prefetch per-node data to regs
    float2 pown[ITEMS], pac[ITEMS];
    int    pmk[ITEMS];
    #pragma unroll
    for (int i = 0; i < ITEMS; ++i) {
        const int n = t + i * THREADS;
        float2 p  = make_float2(0.f, 0.f);
        float2 ac = make_float2(0.f, 0.f);
        int    mk = 0;
        if (n < NP1) {
            p  = pb[n];
            ac = ab[n];
            mk = mb[n];
            unsigned ux = __float_as_uint(p.x);
            unsigned uy = __float_as_uint(p.y);
            ux = (ux + 0x7FFFu + ((ux >> 16) & 1u)) >> 16;          // bf16 RNE
            uy = (uy + 0x7FFFu + ((uy >> 16) & 1u)) & 0xFFFF0000u;  // bf16 RNE
            s_psi[n] = uy | ux;
        }
        pown[i] = p; pac[i] = ac; pmk[i] = mk;
    }
    __syncthreads();

    // ---- phase A: coalesced knn stream, 8 lanes per node
    // lane l handles node g*8 + (l>>3), quarter (l&7); one 1KB wave-load/step
    #pragma unroll 2
    for (int g = wid; g < NGROUPS; g += NWAVES) {
        const int4 id = kb[(size_t)g * 64 + lane];
        const int  n0 = g * 8 + (lane >> 3);

        const unsigned up = s_psi[n0];               // 8-lane broadcast
        const float px = __uint_as_float(up << 16);
        const float py = __uint_as_float(up & 0xFFFF0000u);

        const unsigned u0 = s_psi[id.x];
        const unsigned u1 = s_psi[id.y];
        const unsigned u2 = s_psi[id.z];
        const unsigned u3 = s_psi[id.w];
        const float nsx = __uint_as_float(u0 << 16) + __uint_as_float(u1 << 16)
                        + __uint_as_float(u2 << 16) + __uint_as_float(u3 << 16);
        const float nsy = __uint_as_float(u0 & 0xFFFF0000u) + __uint_as_float(u1 & 0xFFFF0000u)
                        + __uint_as_float(u2 & 0xFFFF0000u) + __uint_as_float(u3 & 0xFFFF0000u);

        float dot = px * nsx + py * nsy;             // partial over 4 neighbors
        dot += __shfl_xor(dot, 1);
        dot += __shfl_xor(dot, 2);
        dot += __shfl_xor(dot, 4);                   // sum over all 32 neighbors
        if ((lane & 7) == 0) s_intf[n0] = dot;
    }
    __syncthreads();

    // ---- phase B: finish scores (no global loads)
    float sc[ITEMS];
    #pragma unroll
    for (int i = 0; i < ITEMS; ++i) {
        const int n = t + i * THREADS;
        float v = -INFINITY;
        if (n < NP1) {
            const float2 p  = pown[i];
            const float2 ac = pac[i];
            const float dx = ac.x - cx, dy = ac.y - cy;
            const float dist = sqrtf(dx * dx + dy * dy);
            v = p.x * qx + p.y * qy + lam * s_intf[n] - mu * dist;
            if (pmk[i] != 0) v = NEG_INF;
        }
        sc[i] = v;
    }

    // ---- block max
    float m = -INFINITY;
    #pragma unroll
    for (int i = 0; i < ITEMS; ++i) m = fmaxf(m, sc[i]);
    #pragma unroll
    for (int off = 32; off > 0; off >>= 1) m = fmaxf(m, __shfl_xor(m, off));
    if (lane == 0) red[wid] = m;
    __syncthreads();
    float M = red[0];
    #pragma unroll
    for (int w = 1; w < NWAVES; ++w) M = fmaxf(M, red[w]);
    __syncthreads();   // red reused below

    // ---- block sum of exp(sc - M)
    float s = 0.f;
    #pragma unroll
    for (int i = 0; i < ITEMS; ++i) s += __expf(sc[i] - M);
    #pragma unroll
    for (int off = 32; off > 0; off >>= 1) s += __shfl_xor(s, off);
    if (lane == 0) red[wid] = s;
    __syncthreads();
    float S = 0.f;
    #pragma unroll
    for (int w = 0; w < NWAVES; ++w) S += red[w];
    const float lse = M + logf(S);

    // ---- write log-softmax
    #pragma unroll
    for (int i = 0; i < ITEMS; ++i) {
        const int n = t + i * THREADS;
        if (n < NP1) out[(long)b * NP1 + n] = sc[i] - lse;
    }
}

extern "C" void kernel_launch(void* const* d_in, const int* in_sizes, int n_in,
                              void* d_out, int out_size, void* d_ws, size_t ws_size,
                              hipStream_t stream) {
    const float* query = (const float*)d_in[0];
    const float* psi   = (const float*)d_in[1];
    const int*   knn   = (const int*)d_in[2];
    const int*   mask  = (const int*)d_in[3];
    const float* cur   = (const float*)d_in[4];
    const float* allc  = (const float*)d_in[5];
    const float* lam   = (const float*)d_in[6];
    const float* mu    = (const float*)d_in[7];
    float* out = (float*)d_out;

    hybrid_scoring_kernel<<<NB, THREADS, 0, stream>>>(
        query, psi, knn, mask, cur, allc, lam, mu, out);
}

// Round 7
// 80.628 us; speedup vs baseline: 4.7923x; 1.1408x over previous
//
#include <hip/hip_runtime.h>

#define NB      256
#define NP1     10000
#define KNN     32
#define THREADS 1024
#define NWAVES  (THREADS / 64)
#define HALF_N  (NP1 / 2)        // 5000 nodes per half-block
#define ITEMS_F 10               // staging iterations for full psi
#define ITEMS_H 5                // per-half items (5000/1024 -> 5)
#define GROUPS_H (HALF_N / 8)    // 625 groups of 8 nodes per half
#define NEG_INF -1000000000.0f

// ---------------- kernel 1: scores + per-half (m, s) ----------------
__global__ __launch_bounds__(THREADS, 8) void hybrid_scores_kernel(
    const float* __restrict__ query,        // [B,2]
    const float* __restrict__ psi,          // [B,NP1,2]
    const int*   __restrict__ knn,          // [B,NP1,K]
    const int*   __restrict__ mask,         // [B,NP1] (bool pushed as int32)
    const float* __restrict__ cur,          // [B,2]
    const float* __restrict__ allc,         // [B,NP1,2]
    const float* __restrict__ lam_p,        // [1]
    const float* __restrict__ mu_p,         // [1]
    float* __restrict__ out,                // [B,NP1] raw scores
    float2* __restrict__ ws_ms)             // [B*2] per-half (m, s)
{
    __shared__ unsigned s_psi[NP1];         // packed bf16 (y<<16 | x), 40 KB
    __shared__ float    s_intf[HALF_N];     // own half interference, 20 KB
    __shared__ float    red[NWAVES];

    // XCD pairing: default dispatch round-robins bid%8 across XCDs.
    // Map so both halves of a row land on the same XCD (psi L2 reuse).
    const int bid  = blockIdx.x;
    const int xcd  = bid & 7;
    const int slot = bid >> 3;              // [0,64)
    const int b    = xcd * 32 + (slot >> 1);
    const int half = slot & 1;

    const int t    = threadIdx.x;
    const int lane = t & 63;
    const int wid  = t >> 6;
    const int nbase = half * HALF_N;

    const float lam = lam_p[0];
    const float mu  = mu_p[0];
    const float qx  = query[2*b],  qy = query[2*b+1];
    const float cx  = cur[2*b],    cy = cur[2*b+1];

    const float2* __restrict__ pb = (const float2*)(psi  + (long)b * NP1 * 2);
    const float2* __restrict__ ab = (const float2*)(allc + (long)b * NP1 * 2);
    const int4*   __restrict__ kb = (const int4*)(knn + (long)b * NP1 * KNN);
    const int*    __restrict__ mb = mask + (long)b * NP1;

    // ---- stage FULL psi[b] into LDS (packed bf16)
    #pragma unroll
    for (int i = 0; i < ITEMS_F; ++i) {
        const int n = t + i * THREADS;
        if (n < NP1) {
            const float2 p = pb[n];
            unsigned ux = __float_as_uint(p.x);
            unsigned uy = __float_as_uint(p.y);
            ux = (ux + 0x7FFFu + ((ux >> 16) & 1u)) >> 16;          // bf16 RNE
            uy = (uy + 0x7FFFu + ((uy >> 16) & 1u)) & 0xFFFF0000u;  // bf16 RNE
            s_psi[n] = uy | ux;
        }
    }

    // ---- prefetch own-half per-node data into regs
    float2 pac[ITEMS_H];
    int    pmk[ITEMS_H];
    #pragma unroll
    for (int i = 0; i < ITEMS_H; ++i) {
        const int ln = t + i * THREADS;
        float2 ac = make_float2(0.f, 0.f);
        int    mk = 0;
        if (ln < HALF_N) {
            ac = ab[nbase + ln];
            mk = mb[nbase + ln];
        }
        pac[i] = ac; pmk[i] = mk;
    }
    __syncthreads();

    // ---- phase A: coalesced knn stream for own half, 8 lanes per node
    const int gbase = half * GROUPS_H;
    #pragma unroll 2
    for (int g = gbase + wid; g < gbase + GROUPS_H; g += NWAVES) {
        const int4 id = kb[(size_t)g * 64 + lane];
        const int  n0 = g * 8 + (lane >> 3);

        const unsigned up = s_psi[n0];               // 8-lane broadcast
        const float px = __uint_as_float(up << 16);
        const float py = __uint_as_float(up & 0xFFFF0000u);

        const unsigned u0 = s_psi[id.x];
        const unsigned u1 = s_psi[id.y];
        const unsigned u2 = s_psi[id.z];
        const unsigned u3 = s_psi[id.w];
        const float nsx = __uint_as_float(u0 << 16) + __uint_as_float(u1 << 16)
                        + __uint_as_float(u2 << 16) + __uint_as_float(u3 << 16);
        const float nsy = __uint_as_float(u0 & 0xFFFF0000u) + __uint_as_float(u1 & 0xFFFF0000u)
                        + __uint_as_float(u2 & 0xFFFF0000u) + __uint_as_float(u3 & 0xFFFF0000u);

        float dot = px * nsx + py * nsy;             // partial over 4 neighbors
        dot += __shfl_xor(dot, 1);
        dot += __shfl_xor(dot, 2);
        dot += __shfl_xor(dot, 4);                   // sum over all 32 neighbors
        if ((lane & 7) == 0) s_intf[n0 - nbase] = dot;
    }
    __syncthreads();

    // ---- phase B: finish scores for own half (no global loads)
    float sc[ITEMS_H];
    #pragma unroll
    for (int i = 0; i < ITEMS_H; ++i) {
        const int ln = t + i * THREADS;
        float v = -INFINITY;
        if (ln < HALF_N) {
            const unsigned up = s_psi[nbase + ln];
            const float px = __uint_as_float(up << 16);
            const float py = __uint_as_float(up & 0xFFFF0000u);
            const float2 ac = pac[i];
            const float dx = ac.x - cx, dy = ac.y - cy;
            const float dist = sqrtf(dx * dx + dy * dy);
            v = px * qx + py * qy + lam * s_intf[ln] - mu * dist;
            if (pmk[i] != 0) v = NEG_INF;
        }
        sc[i] = v;
    }

    // ---- half-block max
    float m = -INFINITY;
    #pragma unroll
    for (int i = 0; i < ITEMS_H; ++i) m = fmaxf(m, sc[i]);
    #pragma unroll
    for (int off = 32; off > 0; off >>= 1) m = fmaxf(m, __shfl_xor(m, off));
    if (lane == 0) red[wid] = m;
    __syncthreads();
    float M = red[0];
    #pragma unroll
    for (int w = 1; w < NWAVES; ++w) M = fmaxf(M, red[w]);
    __syncthreads();   // red reused below

    // ---- half-block sum of exp(sc - M)
    float s = 0.f;
    #pragma unroll
    for (int i = 0; i < ITEMS_H; ++i) s += __expf(sc[i] - M);
    #pragma unroll
    for (int off = 32; off > 0; off >>= 1) s += __shfl_xor(s, off);
    if (lane == 0) red[wid] = s;
    __syncthreads();
    if (t == 0) {
        float S = 0.f;
        #pragma unroll
        for (int w = 0; w < NWAVES; ++w) S += red[w];
        ws_ms[b * 2 + half] = make_float2(M, S);
    }

    // ---- write raw scores
    #pragma unroll
    for (int i = 0; i < ITEMS_H; ++i) {
        const int ln = t + i * THREADS;
        if (ln < HALF_N) out[(long)b * NP1 + nbase + ln] = sc[i];
    }
}

// ---------------- kernel 2: combine (m,s), subtract lse ----------------
#define CHUNK 2500
__global__ __launch_bounds__(THREADS) void hybrid_finalize_kernel(
    float* __restrict__ out, const float2* __restrict__ ws_ms)
{
    const int bid  = blockIdx.x;
    const int b    = bid >> 2;
    const int cnk  = bid & 3;
    const int t    = threadIdx.x;

    const float2 a = ws_ms[b * 2 + 0];
    const float2 c = ws_ms[b * 2 + 1];
    const float M = fmaxf(a.x, c.x);
    const float S = a.y * __expf(a.x - M) + c.y * __expf(c.x - M);
    const float lse = M + logf(S);

    const long base = (long)b * NP1 + cnk * CHUNK;
    #pragma unroll
    for (int i = 0; i < 3; ++i) {
        const int ln = t + i * THREADS;
        if (ln < CHUNK) out[base + ln] -= lse;
    }
}

extern "C" void kernel_launch(void* const* d_in, const int* in_sizes, int n_in,
                              void* d_out, int out_size, void* d_ws, size_t ws_size,
                              hipStream_t stream) {
    const float* query = (const float*)d_in[0];
    const float* psi   = (const float*)d_in[1];
    const int*   knn   = (const int*)d_in[2];
    const int*   mask  = (const int*)d_in[3];
    const float* cur   = (const float*)d_in[4];
    const float* allc  = (const float*)d_in[5];
    const float* lam   = (const float*)d_in[6];
    const float* mu    = (const float*)d_in[7];
    float* out = (float*)d_out;
    float2* ws_ms = (float2*)d_ws;          // 512 float2 = 4 KB

    hybrid_scores_kernel<<<NB * 2, THREADS, 0, stream>>>(
        query, psi, knn, mask, cur, allc, lam, mu, out, ws_ms);
    hybrid_finalize_kernel<<<NB * 4, THREADS, 0, stream>>>(out, ws_ms);
}